// Round 14
// baseline (39.016 us; speedup 1.0000x reference)
//
#include <hip/hip_runtime.h>

// LSTM B=65536, T=9, I=57, H=2 (4H=8) — single-kernel, block-local two-phase,
// staging via __builtin_amdgcn_global_load_lds (direct HBM->LDS, width 16).
//
// R8-R13 evidence: all structural levers null except chunk size; residual
// ~12us over the 21.4us cold-HBM floor attributed to the global->VGPR->
// ds_write staging round-trip (per-chunk serialized waits). Fix: gload_lds
// width-16 (never auto-emitted by compiler; +67% staging A/B in learn_hip
// m193). Chunk layout is linear in lane order == the wave-uniform-base +
// lane*16 HW semantics (m104). One barrier per chunk (m97 pattern): barrier
// drain doubles as "prefetched chunk landed".
// DPP rotate-reduce kept (row_ror:N = dst[i]=src[(i-N)&15], proven R9/R10).

#define B_TOTAL 65536
#define T_STEPS 9
#define I_DIM   57
#define BATCH_PER_BLOCK 64
#define ROWS_PER_BLOCK (BATCH_PER_BLOCK * T_STEPS)   // 576
#define CHUNK_ROWS 64
#define N_CHUNKS   (ROWS_PER_BLOCK / CHUNK_ROWS)     // 9
#define CHUNK_DW   (CHUNK_ROWS * I_DIM)              // 3648 dwords, 14592 B
#define CHUNK_F4   (CHUNK_DW / 4)                    // 912 float4
#define GX_PAD     9                                  // 8 gates + 1 pad
#define NBLOCKS    (B_TOTAL / BATCH_PER_BLOCK)       // 1024

__device__ __forceinline__ float fast_tanh(float v) {
    // tanh(v) = 1 - 2/(exp(2v)+1); exp(2v) = exp2(2*log2e*v). Err ~1e-6.
    float e = __builtin_amdgcn_exp2f(2.885390082f * v);
    return 1.0f - 2.0f * __builtin_amdgcn_rcpf(e + 1.0f);
}
__device__ __forceinline__ float fast_sig(float v) {
    return 0.5f * fast_tanh(0.5f * v) + 0.5f;
}

// row_ror:N within 16-lane DPP rows; CTRL = 0x120 | N (compile-time const).
// Semantics (established by R9 fail / R10 pass): dst[i] = src[(i-N)&15].
#define DPP_ROR_F32(VAR, SRC, CTRL)                                          \
    float VAR = __builtin_bit_cast(float, __builtin_amdgcn_update_dpp(       \
        0, __builtin_bit_cast(int, SRC), (CTRL), 0xF, 0xF, false))

// Direct global->LDS, 16B per lane. gptr: per-lane global address.
// lptr: wave-uniform LDS base; HW stores to lptr + lane*16.
__device__ __forceinline__ void gload_lds16(const float* g, float* l) {
    __builtin_amdgcn_global_load_lds(
        (const __attribute__((address_space(1))) void*)g,
        (__attribute__((address_space(3))) void*)l,
        16, 0, 0);
}

__global__ __launch_bounds__(256)
void lstm_onepass(const float* __restrict__ x,
                  const float* __restrict__ W_ih,
                  const float* __restrict__ W_hh,
                  const float* __restrict__ b_ih,
                  const float* __restrict__ b_hh,
                  const float* __restrict__ fc_w,
                  const float* __restrict__ fc_b,
                  float* __restrict__ out) {
    __shared__ float xs[2][CHUNK_DW];                 // 29184 B staging dbuf
    __shared__ float gxp[ROWS_PER_BLOCK * GX_PAD];    // 20736 B gate pre-acts

    const int tid  = threadIdx.x;
    const int wv   = tid >> 6;          // wave 0..3
    const int lane = tid & 63;
    const int cl   = (lane >> 4) & 3;   // 16-lane cluster (DPP row) 0..3
    const int g    = (lane >> 1) & 7;   // gate lane 0..7
    const int p    = lane & 1;          // row parity within cluster

    // Rotated weight slices: acc[d] accumulates gate (g+d)&7 over slice {g+8k}.
    // wrot[d][7] pairs with broadcast x[56]; only g==0 lane contributes.
    float wrot[8][8];
#pragma unroll
    for (int d = 0; d < 8; ++d) {
        const int gg = (g + d) & 7;
        const float* wr = W_ih + gg * I_DIM;
#pragma unroll
        for (int k = 0; k < 7; ++k) wrot[d][k] = wr[g + 8 * k];
        wrot[d][7] = (g == 0) ? wr[56] : 0.0f;
    }
    float bsum = b_ih[g] + b_hh[g];
#pragma unroll
    for (int d = 0; d < 8; ++d)
#pragma unroll
        for (int k = 0; k < 8; ++k)
            asm volatile("" : "+v"(wrot[d][k]));

    // Block's x tile: 576 rows contiguous, 16B-aligned (576*228 % 16 == 0).
    const float* xblk = x + (size_t)blockIdx.x * (ROWS_PER_BLOCK * I_DIM);

    // Issue direct global->LDS loads for chunk C into buffer S.
    // Linear layout: float4 f goes to LDS byte f*16; per instruction the
    // wave-uniform LDS base is xs[S] + wv*1024 + k*4096 (lane*16 added by HW).
#define GLOAD(C, S) do {                                                    \
        const float* gc_ = xblk + (size_t)(C) * CHUNK_DW;                   \
        float* lb_ = &xs[S][0] + wv * 256;         /* 1024 B = 256 floats */ \
        gload_lds16(gc_ + tid * 4,        lb_);                             \
        gload_lds16(gc_ + (256 + tid) * 4, lb_ + 1024);                     \
        gload_lds16(gc_ + (512 + tid) * 4, lb_ + 2048);                     \
        if (tid < CHUNK_F4 - 768)                                           \
            gload_lds16(gc_ + (768 + tid) * 4, lb_ + 3072);                 \
    } while (0)

    // Compute 2 rows per thread of chunk C from LDS buffer S into gxp.
    // Wave covers rows [wv*16, wv*16+16): iter i -> row wv*16 + i*8 + cl*2 + p.
#define COMPUTE(S, C) do {                                                  \
        _Pragma("unroll")                                                   \
        for (int iter = 0; iter < 2; ++iter) {                              \
            const int rl_ = wv * 16 + iter * 8 + cl * 2 + p;                \
            const float* row_ = xs[S] + rl_ * I_DIM;                        \
            float xv_[8];                                                   \
            _Pragma("unroll")                                               \
            for (int k = 0; k < 7; ++k) xv_[k] = row_[g + 8 * k];           \
            xv_[7] = row_[56];   /* broadcast; pairs with wrot[d][7] */     \
            float acc_[8];                                                  \
            _Pragma("unroll")                                               \
            for (int d = 0; d < 8; ++d) {                                   \
                float s_ = wrot[d][0] * xv_[0];                             \
                _Pragma("unroll")                                           \
                for (int k = 1; k < 8; ++k) s_ += wrot[d][k] * xv_[k];      \
                acc_[d] = s_;                                               \
            }                                                               \
            /* DPP rotate-gather: gate g takes acc[d] from gate (g-d)&7,    \
               same parity: row_ror:(2d). Tree add, VALU-only. */           \
            DPP_ROR_F32(r1_, acc_[1], 0x122);                               \
            DPP_ROR_F32(r2_, acc_[2], 0x124);                               \
            DPP_ROR_F32(r3_, acc_[3], 0x126);                               \
            DPP_ROR_F32(r4_, acc_[4], 0x128);                               \
            DPP_ROR_F32(r5_, acc_[5], 0x12A);                               \
            DPP_ROR_F32(r6_, acc_[6], 0x12C);                               \
            DPP_ROR_F32(r7_, acc_[7], 0x12E);                               \
            float tot_ = ((acc_[0] + r1_) + (r2_ + r3_))                    \
                       + ((r4_ + r5_) + (r6_ + r7_)) + bsum;                \
            gxp[((C) * CHUNK_ROWS + rl_) * GX_PAD + g] = tot_;              \
        }                                                                   \
    } while (0)

    // m97-pattern loop: issue next-chunk gload, compute current, barrier
    // (the barrier's vmcnt drain doubles as "next chunk landed").
    GLOAD(0, 0);
    __syncthreads();                                   // chunk 0 resident

#pragma unroll
    for (int cc = 0; cc < N_CHUNKS; ++cc) {
        if (cc + 1 < N_CHUNKS) GLOAD(cc + 1, (cc + 1) & 1);  // prefetch
        COMPUTE(cc & 1, cc);                                 // hides latency
        __syncthreads();                                     // drain + sync
    }
#undef GLOAD
#undef COMPUTE

    // ---------------- Phase B: recurrence, one wave, 1 thread/batch --------
    if (tid < BATCH_PER_BLOCK) {
        float w0[8], w1[8];
#pragma unroll
        for (int q = 0; q < 8; ++q) {
            w0[q] = W_hh[q * 2];
            w1[q] = W_hh[q * 2 + 1];
        }

        float h0 = 0.f, h1 = 0.f, c0 = 0.f, c1 = 0.f;
        const float* gb = gxp + tid * (T_STEPS * GX_PAD);  // stride 81 floats

#pragma unroll
        for (int t = 0; t < T_STEPS; ++t) {
            const float* pp = gb + t * GX_PAD;
            // gate rows [i0,i1,f0,f1,g0,g1,o0,o1]
            const float i0 = fast_sig (pp[0] + h0 * w0[0] + h1 * w1[0]);
            const float i1 = fast_sig (pp[1] + h0 * w0[1] + h1 * w1[1]);
            const float f0 = fast_sig (pp[2] + h0 * w0[2] + h1 * w1[2]);
            const float f1 = fast_sig (pp[3] + h0 * w0[3] + h1 * w1[3]);
            const float g0 = fast_tanh(pp[4] + h0 * w0[4] + h1 * w1[4]);
            const float g1 = fast_tanh(pp[5] + h0 * w0[5] + h1 * w1[5]);
            const float o0 = fast_sig (pp[6] + h0 * w0[6] + h1 * w1[6]);
            const float o1 = fast_sig (pp[7] + h0 * w0[7] + h1 * w1[7]);
            c0 = f0 * c0 + i0 * g0;
            c1 = f1 * c1 + i1 * g1;
            h0 = o0 * fast_tanh(c0);
            h1 = o1 * fast_tanh(c1);
        }

        out[blockIdx.x * BATCH_PER_BLOCK + tid] =
            h0 * fc_w[0] + h1 * fc_w[1] + fc_b[0];
    }
}

extern "C" void kernel_launch(void* const* d_in, const int* in_sizes, int n_in,
                              void* d_out, int out_size, void* d_ws, size_t ws_size,
                              hipStream_t stream) {
    const float* x    = (const float*)d_in[0];
    const float* W_ih = (const float*)d_in[1];
    const float* W_hh = (const float*)d_in[2];
    const float* b_ih = (const float*)d_in[3];
    const float* b_hh = (const float*)d_in[4];
    const float* fc_w = (const float*)d_in[5];
    const float* fc_b = (const float*)d_in[6];
    float* out = (float*)d_out;

    lstm_onepass<<<dim3(NBLOCKS), dim3(256), 0, stream>>>(
        x, W_ih, W_hh, b_ih, b_hh, fc_w, fc_b, out);
}

// Round 15
// 34.199 us; speedup vs baseline: 1.1409x; 1.1409x over previous
//
#include <hip/hip_runtime.h>

// LSTM B=65536, T=9, I=57, H=2 (4H=8) — wave-private, ZERO-barrier,
// single-LDS-buffer, write-late depth-2 register pipeline.
//
// R8-R14 synthesis: best=R8 (33.7us). Its stall: ds_write(c+1) waits on a
// load issued ~350cy earlier vs ~900cy cold-HBM latency. R12/R13 went
// wave-private but with 8-row chunks (160cy compute) exposure worsened.
// This kernel: 16-row wave chunks (~800cy compute) + write-late: WRITE(c+1)'s
// vmcnt waits on a load issued one full compute phase earlier -> ~satisfied.
// Wave-private in-order DS (R12-validated) makes WAR safe -> SINGLE LDS buf
// per wave: total LDS 35,328B -> 4 blocks/CU co-resident, one generation,
// zero __syncthreads in the kernel.
// DPP rotate-reduce kept (row_ror:N = dst[i]=src[(i-N)&15], proven R9/R10).

#define B_TOTAL 65536
#define T_STEPS 9
#define I_DIM   57
#define BATCH_PER_BLOCK 64
#define ROWS_PER_BLOCK (BATCH_PER_BLOCK * T_STEPS)   // 576
#define ROWS_PER_WAVE  144                            // 16 batches x 9 steps
#define WCH_ROWS 16
#define N_WCH    9                                    // 144 / 16
#define WCH_DW   (WCH_ROWS * I_DIM)                   // 912 dwords, 3648 B
#define WCH_F4   (WCH_DW / 4)                         // 228 float4
#define GX_PAD   9                                    // 8 gates + 1 pad
#define NBLOCKS  (B_TOTAL / BATCH_PER_BLOCK)          // 1024

__device__ __forceinline__ float fast_tanh(float v) {
    // tanh(v) = 1 - 2/(exp(2v)+1); exp(2v) = exp2(2*log2e*v). Err ~1e-6.
    float e = __builtin_amdgcn_exp2f(2.885390082f * v);
    return 1.0f - 2.0f * __builtin_amdgcn_rcpf(e + 1.0f);
}
__device__ __forceinline__ float fast_sig(float v) {
    return 0.5f * fast_tanh(0.5f * v) + 0.5f;
}

// row_ror:N within 16-lane DPP rows; CTRL = 0x120 | N (compile-time const).
// Semantics (established by R9 fail / R10 pass): dst[i] = src[(i-N)&15].
#define DPP_ROR_F32(VAR, SRC, CTRL)                                          \
    float VAR = __builtin_bit_cast(float, __builtin_amdgcn_update_dpp(       \
        0, __builtin_bit_cast(int, SRC), (CTRL), 0xF, 0xF, false))

__global__ __launch_bounds__(256, 4)
void lstm_onepass(const float* __restrict__ x,
                  const float* __restrict__ W_ih,
                  const float* __restrict__ W_hh,
                  const float* __restrict__ b_ih,
                  const float* __restrict__ b_hh,
                  const float* __restrict__ fc_w,
                  const float* __restrict__ fc_b,
                  float* __restrict__ out) {
    __shared__ float xs[4][WCH_DW];                   // 14592 B (1 buf/wave)
    __shared__ float gxp[ROWS_PER_BLOCK * GX_PAD];    // 20736 B
                                                      // total 35328 -> 4 blk/CU
    const int tid  = threadIdx.x;
    const int wv   = tid >> 6;          // wave 0..3 (owns batches wv*16..+15)
    const int lane = tid & 63;
    const int cl   = (lane >> 4) & 3;   // 16-lane cluster (DPP row) 0..3
    const int g    = (lane >> 1) & 7;   // gate lane 0..7
    const int p    = lane & 1;          // row parity within cluster

    // Rotated weight slices over i=0..55: wrot[d][k] = W[(g+d)&7][g+8k].
    // x[56] handled separately as + w56*x56 after the rotate-reduce.
    float wrot[8][7];
#pragma unroll
    for (int d = 0; d < 8; ++d) {
        const int gg = (g + d) & 7;
        const float* wr = W_ih + gg * I_DIM;
#pragma unroll
        for (int k = 0; k < 7; ++k) wrot[d][k] = wr[g + 8 * k];
    }
    float w56  = W_ih[g * I_DIM + 56];
    float bsum = b_ih[g] + b_hh[g];
#pragma unroll
    for (int d = 0; d < 8; ++d)
#pragma unroll
        for (int k = 0; k < 7; ++k)
            asm volatile("" : "+v"(wrot[d][k]));
    asm volatile("" : "+v"(w56), "+v"(bsum));

    // Wave's x region: 144 rows contiguous, 16B-aligned (144*228 = 32832 B).
    const float* xw = x + (size_t)blockIdx.x * (ROWS_PER_BLOCK * I_DIM)
                        + (size_t)wv * (ROWS_PER_WAVE * I_DIM);
    float* xsw = xs[wv];

    // Two named register slots (rule #20), 4 float4 each.
    float4 a0, a1, a2, a3, b0, b1, b2, b3;

#define SLOAD(C, R0, R1, R2, R3) do {                                       \
        const float4* xc_ = (const float4*)(xw + (size_t)(C) * WCH_DW);     \
        R0 = xc_[lane];                                                     \
        R1 = xc_[64 + lane];                                                \
        R2 = xc_[128 + lane];                                               \
        if (lane < WCH_F4 - 192) R3 = xc_[192 + lane];                      \
    } while (0)

#define SWRITE(R0, R1, R2, R3) do {                                         \
        float4* L_ = (float4*)xsw;                                          \
        L_[lane] = R0;                                                      \
        L_[64 + lane] = R1;                                                 \
        L_[128 + lane] = R2;                                                \
        if (lane < WCH_F4 - 192) L_[192 + lane] = R3;                       \
    } while (0)

    // Compute 2 rows per thread (rows iter*8 + cl*2 + p of chunk C).
#define COMPUTE(C) do {                                                     \
        _Pragma("unroll")                                                   \
        for (int iter = 0; iter < 2; ++iter) {                              \
            const int rin_ = iter * 8 + cl * 2 + p;                         \
            const float* row_ = xsw + rin_ * I_DIM;                         \
            float xv_[7];                                                   \
            _Pragma("unroll")                                               \
            for (int k = 0; k < 7; ++k) xv_[k] = row_[g + 8 * k];           \
            const float x56_ = row_[56];                                    \
            float acc_[8];                                                  \
            _Pragma("unroll")                                               \
            for (int d = 0; d < 8; ++d) {                                   \
                float s_ = wrot[d][0] * xv_[0];                             \
                _Pragma("unroll")                                           \
                for (int k = 1; k < 7; ++k) s_ += wrot[d][k] * xv_[k];      \
                acc_[d] = s_;                                               \
            }                                                               \
            /* DPP rotate-gather: gate g takes acc[d] from gate (g-d)&7,    \
               same parity: row_ror:(2d). Tree add, VALU-only. */           \
            DPP_ROR_F32(r1_, acc_[1], 0x122);                               \
            DPP_ROR_F32(r2_, acc_[2], 0x124);                               \
            DPP_ROR_F32(r3_, acc_[3], 0x126);                               \
            DPP_ROR_F32(r4_, acc_[4], 0x128);                               \
            DPP_ROR_F32(r5_, acc_[5], 0x12A);                               \
            DPP_ROR_F32(r6_, acc_[6], 0x12C);                               \
            DPP_ROR_F32(r7_, acc_[7], 0x12E);                               \
            float tot_ = ((acc_[0] + r1_) + (r2_ + r3_))                    \
                       + ((r4_ + r5_) + (r6_ + r7_))                        \
                       + bsum + w56 * x56_;                                 \
            gxp[(wv * ROWS_PER_WAVE + (C) * WCH_ROWS + rin_) * GX_PAD + g]  \
                = tot_;                                                     \
        }                                                                   \
    } while (0)

    // Prologue: chunk0 -> LDS (one exposed cold latency), chunk1 in regs.
    SLOAD(0, a0, a1, a2, a3);
    SWRITE(a0, a1, a2, a3);          // vmcnt wait: unavoidable first fill
    SLOAD(1, b0, b1, b2, b3);

    // Zero-barrier pipeline. Slot of chunk cc is free after the prologue/
    // previous SWRITE, so it reloads chunk cc+2 while chunk cc computes.
    // SWRITE(cc+1) waits on a load issued one full COMPUTE (~800cy) earlier.
    // WAR (write over just-read rows) is safe: per-wave DS ops are in-order.
#pragma unroll
    for (int cc = 0; cc < N_WCH; ++cc) {
        COMPUTE(cc);
        if ((cc & 1) == 0) {
            if (cc + 2 < N_WCH) SLOAD(cc + 2, a0, a1, a2, a3);
            if (cc + 1 < N_WCH) SWRITE(b0, b1, b2, b3);   // chunk cc+1
        } else {
            if (cc + 2 < N_WCH) SLOAD(cc + 2, b0, b1, b2, b3);
            if (cc + 1 < N_WCH) SWRITE(a0, a1, a2, a3);   // chunk cc+1
        }
    }
#undef SLOAD
#undef SWRITE
#undef COMPUTE

    // ---------------- Phase B: recurrence, wave-private, no barrier --------
    // Wave wv wrote gxp rows for batches wv*16..wv*16+15; lanes 0..15 of the
    // same wave consume them (within-wave LDS ordering, R12-validated).
    if (lane < 16) {
        float w0[8], w1[8];
#pragma unroll
        for (int q = 0; q < 8; ++q) {
            w0[q] = W_hh[q * 2];
            w1[q] = W_hh[q * 2 + 1];
        }

        const int bloc = wv * 16 + lane;                   // batch in block
        float h0 = 0.f, h1 = 0.f, c0 = 0.f, c1 = 0.f;
        const float* gb = gxp + bloc * (T_STEPS * GX_PAD); // stride 81 floats
                                                           // (81*lane mod 32
                                                           //  distinct banks)
#pragma unroll
        for (int t = 0; t < T_STEPS; ++t) {
            const float* pp = gb + t * GX_PAD;
            // gate rows [i0,i1,f0,f1,g0,g1,o0,o1]
            const float i0 = fast_sig (pp[0] + h0 * w0[0] + h1 * w1[0]);
            const float i1 = fast_sig (pp[1] + h0 * w0[1] + h1 * w1[1]);
            const float f0 = fast_sig (pp[2] + h0 * w0[2] + h1 * w1[2]);
            const float f1 = fast_sig (pp[3] + h0 * w0[3] + h1 * w1[3]);
            const float g0 = fast_tanh(pp[4] + h0 * w0[4] + h1 * w1[4]);
            const float g1 = fast_tanh(pp[5] + h0 * w0[5] + h1 * w1[5]);
            const float o0 = fast_sig (pp[6] + h0 * w0[6] + h1 * w1[6]);
            const float o1 = fast_sig (pp[7] + h0 * w0[7] + h1 * w1[7]);
            c0 = f0 * c0 + i0 * g0;
            c1 = f1 * c1 + i1 * g1;
            h0 = o0 * fast_tanh(c0);
            h1 = o1 * fast_tanh(c1);
        }

        out[blockIdx.x * BATCH_PER_BLOCK + bloc] =
            h0 * fc_w[0] + h1 * fc_w[1] + fc_b[0];
    }
}

extern "C" void kernel_launch(void* const* d_in, const int* in_sizes, int n_in,
                              void* d_out, int out_size, void* d_ws, size_t ws_size,
                              hipStream_t stream) {
    const float* x    = (const float*)d_in[0];
    const float* W_ih = (const float*)d_in[1];
    const float* W_hh = (const float*)d_in[2];
    const float* b_ih = (const float*)d_in[3];
    const float* b_hh = (const float*)d_in[4];
    const float* fc_w = (const float*)d_in[5];
    const float* fc_b = (const float*)d_in[6];
    float* out = (float*)d_out;

    lstm_onepass<<<dim3(NBLOCKS), dim3(256), 0, stream>>>(
        x, W_ih, W_hh, b_ih, b_hh, fc_w, fc_b, out);
}

// Round 16
// 33.570 us; speedup vs baseline: 1.1622x; 1.0187x over previous
//
#include <hip/hip_runtime.h>

// LSTM B=65536, T=9, I=57, H=2 (4H=8) — single-kernel, block-local two-phase.
// FINAL: this is the empirical-best variant (R8, 33.7us), reinstated after
// 14 structural probes (R2-R15) failed to beat it:
//   shuffle-vs-DPP reduce: null | barriers vs zero-barrier: null |
//   3 vs 4 blocks/CU: null/neg | pipeline depth 1-3: null |
//   global->VGPR->LDS vs global_load_lds: gload_lds worse |
//   two-pass w/ gx HBM round-trip: +8us.
// The op is an irreducible 134.5MB single-use fp32 stream (cold floor 21.4us
// @6.3TB/s); VALU/LDS/VMEM budgets are 4-10us/CU, all under the stream. The
// ~12us residual is structure-invariant => practical short-dispatch stream
// floor on this harness. Phase A: 9x 14.6KB chunks double-buffered through
// LDS (float4 stage), 8-lane-group rotated dot (validated exact in R3),
// __shfl rotate-reduce. Phase B: 1 thread/batch recurrence from padded LDS.

#define B_TOTAL 65536
#define T_STEPS 9
#define I_DIM   57
#define BATCH_PER_BLOCK 64
#define ROWS_PER_BLOCK (BATCH_PER_BLOCK * T_STEPS)   // 576
#define CHUNK_ROWS 64
#define N_CHUNKS   (ROWS_PER_BLOCK / CHUNK_ROWS)     // 9
#define CHUNK_DW   (CHUNK_ROWS * I_DIM)              // 3648 dwords, 14592 B
#define CHUNK_F4   (CHUNK_DW / 4)                    // 912
#define GX_PAD     9                                  // 8 gates + 1 pad
#define NBLOCKS    (B_TOTAL / BATCH_PER_BLOCK)       // 1024

__device__ __forceinline__ float fast_tanh(float v) {
    // tanh(v) = 1 - 2/(exp(2v)+1); exp(2v) = exp2(2*log2e*v). Err ~1e-6.
    float e = __builtin_amdgcn_exp2f(2.885390082f * v);
    return 1.0f - 2.0f * __builtin_amdgcn_rcpf(e + 1.0f);
}
__device__ __forceinline__ float fast_sig(float v) {
    return 0.5f * fast_tanh(0.5f * v) + 0.5f;
}

__global__ __launch_bounds__(256)
void lstm_onepass(const float* __restrict__ x,
                  const float* __restrict__ W_ih,
                  const float* __restrict__ W_hh,
                  const float* __restrict__ b_ih,
                  const float* __restrict__ b_hh,
                  const float* __restrict__ fc_w,
                  const float* __restrict__ fc_b,
                  float* __restrict__ out) {
    __shared__ float xs[2][CHUNK_DW];                 // 29184 B staging dbuf
    __shared__ float gxp[ROWS_PER_BLOCK * GX_PAD];    // 20736 B gate pre-acts

    const int tid = threadIdx.x;
    const int j   = tid & 7;     // gate lane
    const int grp = tid >> 3;    // row group within block, 0..31

    // Rotated weight slices (validated R3: exact). acc_[d] -> gate (j+d)&7.
    float wrot[8][8];
#pragma unroll
    for (int d = 0; d < 8; ++d) {
        const int g = (j + d) & 7;
        const float* wr = W_ih + g * I_DIM;
#pragma unroll
        for (int k = 0; k < 7; ++k) wrot[d][k] = wr[j + 8 * k];
        wrot[d][7] = (j == 0) ? wr[56] : 0.0f;
    }
    float bsum = b_ih[j] + b_hh[j];
#pragma unroll
    for (int d = 0; d < 8; ++d)
#pragma unroll
        for (int k = 0; k < 8; ++k)
            asm volatile("" : "+v"(wrot[d][k]));

    // Block's x tile: 576 rows, contiguous, 16B-aligned (576*228 % 16 == 0).
    const float* xblk = x + (size_t)blockIdx.x * (ROWS_PER_BLOCK * I_DIM);

    float4 st0, st1, st2, st3;

#define STAGE_LOAD(C) do {                                                  \
        const float4* xc_ = (const float4*)(xblk + (size_t)(C) * CHUNK_DW); \
        st0 = xc_[tid];                                                     \
        st1 = xc_[256 + tid];                                               \
        st2 = xc_[512 + tid];                                               \
        if (tid < CHUNK_F4 - 768) st3 = xc_[768 + tid];                     \
    } while (0)

#define STAGE_WRITE(S) do {                                                 \
        float4* L_ = (float4*)xs[S];                                        \
        L_[tid] = st0;                                                      \
        L_[256 + tid] = st1;                                                \
        L_[512 + tid] = st2;                                                \
        if (tid < CHUNK_F4 - 768) L_[768 + tid] = st3;                      \
    } while (0)

    // Compute 2 rows (grp, grp+32) of chunk C from LDS buffer S into gxp.
#define COMPUTE(S, C) do {                                                  \
        _Pragma("unroll")                                                   \
        for (int iter = 0; iter < 2; ++iter) {                              \
            const int rl_ = iter * 32 + grp;                                \
            const float* row_ = xs[S] + rl_ * I_DIM;                        \
            float xv_[8];                                                   \
            _Pragma("unroll")                                               \
            for (int k = 0; k < 7; ++k) xv_[k] = row_[j + 8 * k];           \
            xv_[7] = row_[56];   /* broadcast; pairs with wrot[d][7] */     \
            float acc_[8];                                                  \
            _Pragma("unroll")                                               \
            for (int d = 0; d < 8; ++d) {                                   \
                float s_ = wrot[d][0] * xv_[0];                             \
                _Pragma("unroll")                                           \
                for (int k = 1; k < 8; ++k) s_ += wrot[d][k] * xv_[k];      \
                acc_[d] = s_;                                               \
            }                                                               \
            /* rotate-gather (independent shuffles), explicit tree add */   \
            float t1_ = __shfl(acc_[1], (j - 1) & 7, 8);                    \
            float t2_ = __shfl(acc_[2], (j - 2) & 7, 8);                    \
            float t3_ = __shfl(acc_[3], (j - 3) & 7, 8);                    \
            float t4_ = __shfl(acc_[4], (j - 4) & 7, 8);                    \
            float t5_ = __shfl(acc_[5], (j - 5) & 7, 8);                    \
            float t6_ = __shfl(acc_[6], (j - 6) & 7, 8);                    \
            float t7_ = __shfl(acc_[7], (j - 7) & 7, 8);                    \
            float tot_ = ((acc_[0] + t1_) + (t2_ + t3_))                    \
                       + ((t4_ + t5_) + (t6_ + t7_)) + bsum;                \
            gxp[((C) * CHUNK_ROWS + rl_) * GX_PAD + j] = tot_;              \
        }                                                                   \
    } while (0)

    STAGE_LOAD(0);
    STAGE_WRITE(0);

#pragma unroll
    for (int cc = 0; cc < N_CHUNKS; ++cc) {
        __syncthreads();                               // xs[cc&1] ready
        if (cc + 1 < N_CHUNKS) STAGE_LOAD(cc + 1);     // issue early
        COMPUTE(cc & 1, cc);                           // hides HBM latency
        if (cc + 1 < N_CHUNKS) STAGE_WRITE((cc + 1) & 1);
    }
#undef STAGE_LOAD
#undef STAGE_WRITE
#undef COMPUTE

    __syncthreads();   // gxp complete

    // ---------------- Phase B: recurrence, one wave, 1 thread/batch --------
    if (tid < BATCH_PER_BLOCK) {
        float w0[8], w1[8];
#pragma unroll
        for (int g = 0; g < 8; ++g) {
            w0[g] = W_hh[g * 2];
            w1[g] = W_hh[g * 2 + 1];
        }

        float h0 = 0.f, h1 = 0.f, c0 = 0.f, c1 = 0.f;
        const float* gb = gxp + tid * (T_STEPS * GX_PAD);  // stride 81 floats

#pragma unroll
        for (int t = 0; t < T_STEPS; ++t) {
            const float* p = gb + t * GX_PAD;
            // gate rows [i0,i1,f0,f1,g0,g1,o0,o1]
            const float i0 = fast_sig (p[0] + h0 * w0[0] + h1 * w1[0]);
            const float i1 = fast_sig (p[1] + h0 * w0[1] + h1 * w1[1]);
            const float f0 = fast_sig (p[2] + h0 * w0[2] + h1 * w1[2]);
            const float f1 = fast_sig (p[3] + h0 * w0[3] + h1 * w1[3]);
            const float g0 = fast_tanh(p[4] + h0 * w0[4] + h1 * w1[4]);
            const float g1 = fast_tanh(p[5] + h0 * w0[5] + h1 * w1[5]);
            const float o0 = fast_sig (p[6] + h0 * w0[6] + h1 * w1[6]);
            const float o1 = fast_sig (p[7] + h0 * w0[7] + h1 * w1[7]);
            c0 = f0 * c0 + i0 * g0;
            c1 = f1 * c1 + i1 * g1;
            h0 = o0 * fast_tanh(c0);
            h1 = o1 * fast_tanh(c1);
        }

        out[blockIdx.x * BATCH_PER_BLOCK + tid] =
            h0 * fc_w[0] + h1 * fc_w[1] + fc_b[0];
    }
}

extern "C" void kernel_launch(void* const* d_in, const int* in_sizes, int n_in,
                              void* d_out, int out_size, void* d_ws, size_t ws_size,
                              hipStream_t stream) {
    const float* x    = (const float*)d_in[0];
    const float* W_ih = (const float*)d_in[1];
    const float* W_hh = (const float*)d_in[2];
    const float* b_ih = (const float*)d_in[3];
    const float* b_hh = (const float*)d_in[4];
    const float* fc_w = (const float*)d_in[5];
    const float* fc_b = (const float*)d_in[6];
    float* out = (float*)d_out;

    lstm_onepass<<<dim3(NBLOCKS), dim3(256), 0, stream>>>(
        x, W_ih, W_hh, b_ih, b_hh, fc_w, fc_b, out);
}